// Round 15
// baseline (179.177 us; speedup 1.0000x reference)
//
#include <hip/hip_runtime.h>
#include <math.h>

// Problem constants (from setup_inputs): N=8, H=768, W=360, D=512
#define N_IMG 8
#define H 768
#define W 360
#define D 512
#define SY 383.5f         // (H-1)/2
#define SC 0.00436332312998582394f  // pi/(2W) = pi/720
#define NC 24             // 768/32 m-chunks
#define IPAD 384          // i dimension padded 360 -> 384
#define KSTEPS 10         // 10 x 32 = K 320 band

typedef __fp16 h2 __attribute__((ext_vector_type(2)));
struct H2X2 { h2 a, b; };        // 8B LDS entry: {img01@y, img23@y}
typedef short short8 __attribute__((ext_vector_type(8)));   // 8 bf16 (4 VGPRs)
typedef float f32x4 __attribute__((ext_vector_type(4)));

// fp32 -> bf16 pair, round-to-nearest-even, packed into one uint
__device__ inline unsigned bf16pair(float a, float b) {
    unsigned ua = __builtin_bit_cast(unsigned, a);
    unsigned ub = __builtin_bit_cast(unsigned, b);
    ua += 0x7FFFu + ((ua >> 16) & 1u);
    ub += 0x7FFFu + ((ub >> 16) & 1u);
    return (ua >> 16) | (ub & 0xFFFF0000u);
}

// ---------------------------------------------------------------------------
// Kernel 1 (pre): ALL independent prep in one launch, no internal cross-block
// dependencies (kills one kernel boundary on the critical path).
//  - all 579 blocks: zero the atomic output (2 guarded float4/thread).
//  - blocks 0..575: A-matrix transpose + bf16 pack (px == i exactly ->
//    rc[n][i][m] = radon[n][m][i]); 2 256-thread tile-units/block.
//  - blocks 576..578: SELF-CONTAINED Bg build: each block computes the
//    159-value g-window its 4 ksteps need (g[d] = (1/H) sum hG[k] cos(...),
//    2 threads/value x 384 terms, hw v_cos), then packs the B-frag table
//    with SC pre-folded. Compact layout: Bg[(t*2+j)*64+L], j in {0,1}.
// ---------------------------------------------------------------------------
__global__ __launch_bounds__(512)
void k_pre(const float* __restrict__ radon, const float* __restrict__ hG,
           uint4* __restrict__ rcC, uint4* __restrict__ Bg,
           float4* __restrict__ out4) {
    __shared__ __align__(16) float smem[2 * 32 * 65];   // 16.6 KB, re-purposed
    const int bid = blockIdx.x, tid = threadIdx.x;

    // zero output: 579*512*2 = 592,896 slots >= 524,288 float4 (8 MB)
    {
        int e = (bid * 512 + tid) * 2;
        if (e < 524288)     out4[e]     = make_float4(0.f, 0.f, 0.f, 0.f);
        if (e + 1 < 524288) out4[e + 1] = make_float4(0.f, 0.f, 0.f, 0.f);
    }

    if (bid < 576) {
        // ----- rc transpose (2 tile-units per block) -----
        float (*xs)[65] = (float(*)[65])(smem + (tid >> 8) * (32 * 65));
        const int sub  = tid & 255;
        const int tv = bid * 2 + (tid >> 8);   // 0..1151

        const int i0 = (tv % 6) * 64;
        const int c  = (tv / 6) % NC;
        const int n  = tv / 144;

        {
            int mr    = sub >> 3;          // 0..31
            int lane8 = sub & 7;
            int ib = i0 + lane8 * 8;
            const float* src = radon + ((size_t)n * H + 32 * c + mr) * W + ib;
            float4 v0 = make_float4(0.f, 0.f, 0.f, 0.f), v1 = v0;
            if (ib + 7 < W) {              // 360 % 8 == 0: all-valid or all-invalid
                v0 = *(const float4*)src;
                v1 = *(const float4*)(src + 4);
            }
            *(float4*)&xs[mr][lane8 * 8]     = v0;
            *(float4*)&xs[mr][lane8 * 8 + 4] = v1;
        }
        __syncthreads();

        const int il  = sub >> 2;          // 0..63
        const int oct = sub & 3;
        float v[8];
#pragma unroll
        for (int s = 0; s < 8; ++s) v[s] = xs[oct * 8 + s][il];
        rcC[(((size_t)n * NC + c) * IPAD + i0 + il) * 4 + oct] =
            (uint4){bf16pair(v[0], v[1]), bf16pair(v[2], v[3]),
                    bf16pair(v[4], v[5]), bf16pair(v[6], v[7])};
    } else {
        // ----- self-contained g-window + Bg pack -----
        float* hgs = smem;            // [0, 768)
        float* gl  = smem + 768;      // [768, 928): 159-value window
        const int b = bid - 576;      // 0..2
        const int lo = 1 - 128 * b;   // window start: d in [lo, lo+158]

        hgs[tid] = hG[tid];
        if (tid < 256) hgs[512 + tid] = hG[512 + tid];
        __syncthreads();

        if (tid < 318) {
            int l = tid >> 1, h = tid & 1;
            int d = lo + l;
            int dm = d + ((d < 0) ? H : 0);
            float s = 0.f;
#pragma unroll 4
            for (int q = 0; q < 384; ++q) {
                int k = 384 * h + q;
                int prod = (k * dm) % H;
                s += hgs[k] * __builtin_amdgcn_cosf((float)prod * (1.0f / 768.0f));
            }
            s += __shfl_xor(s, 1);
            if (h == 0) gl[l] = s * (1.0f / (float)H);
        }
        __syncthreads();

        int idx = b * 512 + tid;      // compact table: 1280 uint4 (20 KB)
        if (idx < 1280) {
            int L   = idx & 63;
            int tj2 = idx >> 6;       // t*2 + j
            int t   = tj2 >> 1, j = tj2 & 1;
            int nn  = 16 * j + (L & 15);
            int kb  = 32 * t + (L >> 4) * 8;
            float bf[8];
#pragma unroll
            for (int s = 0; s < 8; ++s)
                bf[s] = SC * gl[nn + 128 - (kb + s) - lo];   // SC pre-folded
            Bg[idx] = (uint4){bf16pair(bf[0], bf[1]), bf16pair(bf[2], bf[3]),
                              bf16pair(bf[4], bf[5]), bf16pair(bf[6], bf[7])};
        }
    }
}

// ---------------------------------------------------------------------------
// Kernel 2: banded circulant MFMA GEMM (round-14 verified). 2 256-thread
// units/block; unit = 16 i x 32 y tile, wave w = image grp*4+w; 1 A-frag +
// 2 B-frags + 2 MFMA per kstep, barrier-free K-loop. SC already folded into
// Bg. Epilogue: fp16 exchange through LDS, coalesced uint2 stores.
// 552 blocks x 512 thr.
// ---------------------------------------------------------------------------
__global__ __launch_bounds__(512)
void k_gemm(const uint4* __restrict__ rcC, const uint4* __restrict__ Bg,
            unsigned short* __restrict__ colp) {
    __shared__ _Float16 lx2[2][16][32][4];   // 8 KB
    const int bid = blockIdx.x, tid = threadIdx.x;

    const int unit = tid >> 8;
    const int sub  = tid & 255;
    const int u = bid * 2 + unit;      // 0..1103
    _Float16 (*lx)[32][4] = lx2[unit];

    const int yt  = u % 24;
    const int it  = (u / 24) % 23;
    const int grp = u / (24 * 23);
    const int i0 = it * 16, y0 = yt * 32;
    const int wv = sub >> 6, L = sub & 63;

    const int c0 = (yt + 20) % NC;     // first band chunk: (y0-128)/32 mod 24
    const uint4* An = rcC + (size_t)(grp * 4 + wv) * NC * IPAD * 4;
    const int arow = i0 + (L & 15);
    const int aoff = L >> 4;

    f32x4 acc0 = (f32x4){0.f, 0.f, 0.f, 0.f};
    f32x4 acc1 = (f32x4){0.f, 0.f, 0.f, 0.f};

    for (int t = 0; t < KSTEPS; ++t) {
        int c = c0 + t;
        c -= (c >= NC) ? NC : 0;
        short8 a = __builtin_bit_cast(short8, An[((size_t)c * IPAD + arow) * 4 + aoff]);
        short8 b0 = __builtin_bit_cast(short8, Bg[(t * 2 + 0) * 64 + L]);
        short8 b1 = __builtin_bit_cast(short8, Bg[(t * 2 + 1) * 64 + L]);
        acc0 = __builtin_amdgcn_mfma_f32_16x16x32_bf16(a, b0, acc0, 0, 0, 0);
        acc1 = __builtin_amdgcn_mfma_f32_16x16x32_bf16(a, b1, acc1, 0, 0, 0);
    }

#pragma unroll
    for (int r = 0; r < 4; ++r) {
        int ilc = (L >> 4) * 4 + r;
        lx[ilc][(L & 15)][wv]      = (_Float16)acc0[r];
        lx[ilc][16 + (L & 15)][wv] = (_Float16)acc1[r];
    }
    __syncthreads();

    unsigned short* cp = colp + (size_t)grp * W * H * 4;
#pragma unroll
    for (int k2 = 0; k2 < 2; ++k2) {
        int e = sub + k2 * 256;        // 0..511
        int ilc = e >> 5, ylc = e & 31;
        int ig = i0 + ilc;
        if (ig < W) {
            uint2 v = *(const uint2*)&lx[ilc][ylc][0];
            *(uint2*)&cp[((size_t)ig * H + y0 + ylc) * 4] = v;
        }
    }
}

// ---------------------------------------------------------------------------
// Kernel 3: backprojection, 4 images/block (proven 101.5 us: LDS-pipe bound,
// conflicts 0, FETCH 2.2 MB). In-prologue angle constants; zero-conflict
// 8B-entry LDS; fp16 packed accumulation flushed every 16 angles; atomicAdd
// into zeroed output; XCD swizzle bz = bid & 7. Grid 1024 x 512 thr.
// ---------------------------------------------------------------------------
__global__ __launch_bounds__(512, 8)
void k_bp(const unsigned short* __restrict__ colp, float* __restrict__ outb) {
    __shared__ __align__(16) H2X2 colh[2][H];   // 12 KB
    __shared__ float2 angs[W / 4];              // 720 B

    const int bid = blockIdx.x;
    const int bz  = bid & 7;             // XCD-local under round-robin dispatch
    const int tle = bid >> 3;            // 0..127: 16 u-tiles x 8 v-tiles
    const int g  = bz >> 2;              // image-group
    const int aq = bz & 3;               // angle quarter
    const int a0 = aq * (W / 4);         // 90 angles per block
    const int u0 = (tle >> 3) * 32;
    const int v0 = (tle & 7) * 64;
    const int tid = threadIdx.x;
    const int lane = tid & 63;
    const int tu = tid >> 6;             // 0..7

    const float vf = (float)(v0 + lane - D / 2);
    float uf[4];
#pragma unroll
    for (int r = 0; r < 4; ++r) uf[r] = (float)(u0 + tu + 8 * r - D / 2);

    const h2 hz = {(__fp16)0.f, (__fp16)0.f};
    float acc[4][4];
    h2 haccA[4], haccB[4];
#pragma unroll
    for (int r = 0; r < 4; ++r) {
#pragma unroll
        for (int nn = 0; nn < 4; ++nn) acc[r][nn] = 0.f;
        haccA[r] = hz;
        haccB[r] = hz;
    }

    const uint2* cp = (const uint2*)colp + (size_t)g * W * H;
    const int y1 = tid;                  // 0..511
    const int y2 = tid + 512;            // 512..767 (tid < 256 only)

    if (tid < W / 4) {
        float th = (float)(a0 + tid) * 0.00872664625997164788f;  // pi/360
        float r = SY / 384.0f;
        angs[tid] = make_float2(cosf(th) * r, -sinf(th) * r);
    }
    {
        const int ab = a0 * H;
        colh[0][y1] = __builtin_bit_cast(H2X2, cp[ab + y1]);
        if (tid < 256) colh[0][y2] = __builtin_bit_cast(H2X2, cp[ab + y2]);
    }
    __syncthreads();

    for (int j = 0; j < W / 4; ++j) {
        int a = a0 + j;
        int an = (j + 1 < W / 4) ? (a + 1) : a;
        const int ab = an * H;
        uint2 d = cp[ab + y1];
        uint2 e = make_uint2(0u, 0u);
        if (tid < 256) e = cp[ab + y2];

        const int cb2 = j & 1;
        float2 AB = angs[j];             // LDS broadcast
        float base = fmaf(vf, AB.x, SY);
#pragma unroll
        for (int r = 0; r < 4; ++r) {
            float py = fmaf(uf[r], AB.y, base);
            float wy = __builtin_amdgcn_fractf(py);
            int iy = (int)py;            // trunc == floor (py > 0)
            uint2 lo_raw = *(const uint2*)&colh[cb2][iy];       // ds_read_b64
            uint2 hi_raw = *(const uint2*)&colh[cb2][iy + 1];   // ds_read_b64
            H2X2 lo = __builtin_bit_cast(H2X2, lo_raw);
            H2X2 hi = __builtin_bit_cast(H2X2, hi_raw);
            h2 wy2 = __builtin_amdgcn_cvt_pkrtz(wy, wy);
            haccA[r] += lo.a + wy2 * (hi.a - lo.a);
            haccB[r] += lo.b + wy2 * (hi.b - lo.b);
        }

        if ((j & 15) == 15) {
#pragma unroll
            for (int r = 0; r < 4; ++r) {
                acc[r][0] += (float)haccA[r].x;
                acc[r][1] += (float)haccA[r].y;
                acc[r][2] += (float)haccB[r].x;
                acc[r][3] += (float)haccB[r].y;
                haccA[r] = hz;
                haccB[r] = hz;
            }
        }

        colh[cb2 ^ 1][y1] = __builtin_bit_cast(H2X2, d);
        if (tid < 256) colh[cb2 ^ 1][y2] = __builtin_bit_cast(H2X2, e);
        __syncthreads();
    }

#pragma unroll
    for (int r = 0; r < 4; ++r) {
        acc[r][0] += (float)haccA[r].x;
        acc[r][1] += (float)haccA[r].y;
        acc[r][2] += (float)haccB[r].x;
        acc[r][3] += (float)haccB[r].y;
        int u = u0 + tu + 8 * r;
#pragma unroll
        for (int nn = 0; nn < 4; ++nn) {
            size_t idx = ((size_t)(g * 4 + nn) * D + u) * D + v0 + lane;
            atomicAdd(&outb[idx], acc[r][nn]);
        }
    }
}

// ---------------------------------------------------------------------------
// Workspace layout:
//   [8192, 28672)          Bg (1280 uint4 = 20 KB compact B-frag table, xSC)
//   [65536, 4489216)       colp (2 grp x 360 x 768 x 8B fp16-packed columns)
//   [4489216, 9207808)     rcC (8 x 24 x 384 x 64B bf16 A-frag chunks)
// ---------------------------------------------------------------------------
extern "C" void kernel_launch(void* const* d_in, const int* in_sizes, int n_in,
                              void* d_out, int out_size, void* d_ws, size_t ws_size,
                              hipStream_t stream) {
    const float* radon = (const float*)d_in[0];
    const float* hG    = (const float*)d_in[1];
    float* out = (float*)d_out;

    uint4* Bg   = (uint4*)((char*)d_ws + 8192);
    unsigned short* colp = (unsigned short*)((char*)d_ws + 65536);
    uint4* rcC  = (uint4*)((char*)d_ws + 4489216);

    k_pre<<<579, 512, 0, stream>>>(radon, hG, rcC, Bg, (float4*)out);
    k_gemm<<<552, 512, 0, stream>>>(rcC, Bg, colp);
    k_bp<<<1024, 512, 0, stream>>>(colp, out);
}

// Round 16
// 176.809 us; speedup vs baseline: 1.0134x; 1.0134x over previous
//
#include <hip/hip_runtime.h>
#include <math.h>

// Problem constants (from setup_inputs): N=8, H=768, W=360, D=512
#define N_IMG 8
#define H 768
#define W 360
#define D 512
#define SY 383.5f         // (H-1)/2
#define SC 0.00436332312998582394f  // pi/(2W) = pi/720
#define NC 24             // 768/32 m-chunks
#define IPAD 384          // i dimension padded 360 -> 384
#define KSTEPS 10         // 10 x 32 = K 320 band

typedef __fp16 h2 __attribute__((ext_vector_type(2)));
struct H2X2 { h2 a, b; };        // 8B LDS entry: {img01@y, img23@y}
typedef short short8 __attribute__((ext_vector_type(8)));   // 8 bf16 (4 VGPRs)
typedef float f32x4 __attribute__((ext_vector_type(4)));

// fp32 -> bf16 pair, round-to-nearest-even, packed into one uint
__device__ inline unsigned bf16pair(float a, float b) {
    unsigned ua = __builtin_bit_cast(unsigned, a);
    unsigned ub = __builtin_bit_cast(unsigned, b);
    ua += 0x7FFFu + ((ua >> 16) & 1u);
    ub += 0x7FFFu + ((ub >> 16) & 1u);
    return (ua >> 16) | (ub & 0xFFFF0000u);
}

// fp16 pair difference: {n.a - b.a, n.b - b.b} (v_pk_sub_f16)
__device__ inline H2X2 h2pdiff(uint2 nraw, uint2 braw) {
    H2X2 nv = __builtin_bit_cast(H2X2, nraw);
    H2X2 bv = __builtin_bit_cast(H2X2, braw);
    H2X2 d;
    d.a = nv.a - bv.a;
    d.b = nv.b - bv.b;
    return d;
}

// ---------------------------------------------------------------------------
// Kernel 1: g[m] = (1/H) sum_k hG[k] cos(2*pi*k*m/H)  (blocks 0..767, 512-thr
// block reduction over 768 k-terms) + zero the atomic output (all 1024
// blocks x 512 thr x 1 float4 = exactly 8 MB).  [r14 verbatim]
// ---------------------------------------------------------------------------
__global__ __launch_bounds__(512)
void k_p0(const float* __restrict__ hG, float* __restrict__ g,
          float4* __restrict__ out4) {
    __shared__ float lred[8];
    const int bid = blockIdx.x, tid = threadIdx.x;

    out4[bid * 512 + tid] = make_float4(0.f, 0.f, 0.f, 0.f);
    if (bid < H) {
        int m = bid;
        int p0 = (tid * m) % H;
        float s = hG[tid] * cosf((float)p0 * 0.00818123086872313911f);  // 2pi/768
        if (tid < 256) {
            int k = tid + 512;
            int p1 = (k * m) % H;
            s += hG[k] * cosf((float)p1 * 0.00818123086872313911f);
        }
#pragma unroll
        for (int off = 32; off > 0; off >>= 1) s += __shfl_down(s, off);
        if ((tid & 63) == 0) lred[tid >> 6] = s;
        __syncthreads();
        if (tid == 0) {
            float t = 0.f;
#pragma unroll
            for (int w2 = 0; w2 < 8; ++w2) t += lred[w2];
            g[m] = t * (1.0f / (float)H);
        }
    }
}

// ---------------------------------------------------------------------------
// Kernel 2: blocks 0..575: A-matrix transpose + bf16 pack (px == i exactly ->
// rc[n][i][m] = radon[n][m][i]); blocks 576..580: MFMA B-frag table from g.
// [r14 verbatim]
// ---------------------------------------------------------------------------
__global__ __launch_bounds__(512)
void k_p1(const float* __restrict__ radon, const float* __restrict__ g,
          uint4* __restrict__ rcC, uint4* __restrict__ Bg) {
    __shared__ float xs2[2][32][65];   // 16.6 KB
    const int bid = blockIdx.x, tid = threadIdx.x;

    if (bid < 576) {
        const int unit = tid >> 8;         // 0/1
        const int sub  = tid & 255;
        const int tv = bid * 2 + unit;     // 0..1151
        float (*xs)[65] = xs2[unit];

        const int i0 = (tv % 6) * 64;
        const int c  = (tv / 6) % NC;
        const int n  = tv / 144;

        {
            int mr    = sub >> 3;          // 0..31
            int lane8 = sub & 7;
            int ib = i0 + lane8 * 8;
            const float* src = radon + ((size_t)n * H + 32 * c + mr) * W + ib;
            float4 v0 = make_float4(0.f, 0.f, 0.f, 0.f), v1 = v0;
            if (ib + 7 < W) {              // 360 % 8 == 0: all-valid or all-invalid
                v0 = *(const float4*)src;
                v1 = *(const float4*)(src + 4);
            }
            *(float4*)&xs[mr][lane8 * 8]     = v0;
            *(float4*)&xs[mr][lane8 * 8 + 4] = v1;
        }
        __syncthreads();

        const int il  = sub >> 2;          // 0..63
        const int oct = sub & 3;
        float v[8];
#pragma unroll
        for (int s = 0; s < 8; ++s) v[s] = xs[oct * 8 + s][il];
        rcC[(((size_t)n * NC + c) * IPAD + i0 + il) * 4 + oct] =
            (uint4){bf16pair(v[0], v[1]), bf16pair(v[2], v[3]),
                    bf16pair(v[4], v[5]), bf16pair(v[6], v[7])};
    } else if (bid < 581) {
        int idx = (bid - 576) * 512 + tid;   // 0..2559
        int L  = idx & 63;
        int tj = idx >> 6;                   // t*4 + j
        int nn = (tj & 3) * 16 + (L & 15);
        int kb = (tj >> 2) * 32 + (L >> 4) * 8;
        float bf[8];
#pragma unroll
        for (int s = 0; s < 8; ++s) {
            int d = nn + 128 - (kb + s);
            d += (d < 0) ? H : 0;
            bf[s] = g[d];
        }
        Bg[idx] = (uint4){bf16pair(bf[0], bf[1]), bf16pair(bf[2], bf[3]),
                          bf16pair(bf[4], bf[5]), bf16pair(bf[6], bf[7])};
    }
}

// ---------------------------------------------------------------------------
// Kernel 3: banded circulant MFMA GEMM. [r14 verbatim]
// ---------------------------------------------------------------------------
__global__ __launch_bounds__(512)
void k_p2(const uint4* __restrict__ rcC, const uint4* __restrict__ Bg,
          unsigned short* __restrict__ colp) {
    __shared__ _Float16 lx2[2][16][32][4];   // 8 KB
    const int bid = blockIdx.x, tid = threadIdx.x;

    const int unit = tid >> 8;
    const int sub  = tid & 255;
    const int u = bid * 2 + unit;      // 0..1103
    _Float16 (*lx)[32][4] = lx2[unit];

    const int yt  = u % 24;
    const int it  = (u / 24) % 23;
    const int grp = u / (24 * 23);
    const int i0 = it * 16, y0 = yt * 32;
    const int wv = sub >> 6, L = sub & 63;

    const int c0 = (yt + 20) % NC;     // first band chunk: (y0-128)/32 mod 24
    const uint4* An = rcC + (size_t)(grp * 4 + wv) * NC * IPAD * 4;
    const int arow = i0 + (L & 15);
    const int aoff = L >> 4;

    f32x4 acc0 = (f32x4){0.f, 0.f, 0.f, 0.f};
    f32x4 acc1 = (f32x4){0.f, 0.f, 0.f, 0.f};

    for (int t = 0; t < KSTEPS; ++t) {
        int c = c0 + t;
        c -= (c >= NC) ? NC : 0;
        short8 a = __builtin_bit_cast(short8, An[((size_t)c * IPAD + arow) * 4 + aoff]);
        short8 b0 = __builtin_bit_cast(short8, Bg[(t * 4 + 0) * 64 + L]);
        short8 b1 = __builtin_bit_cast(short8, Bg[(t * 4 + 1) * 64 + L]);
        acc0 = __builtin_amdgcn_mfma_f32_16x16x32_bf16(a, b0, acc0, 0, 0, 0);
        acc1 = __builtin_amdgcn_mfma_f32_16x16x32_bf16(a, b1, acc1, 0, 0, 0);
    }

#pragma unroll
    for (int r = 0; r < 4; ++r) {
        int ilc = (L >> 4) * 4 + r;
        lx[ilc][(L & 15)][wv]      = (_Float16)(acc0[r] * SC);
        lx[ilc][16 + (L & 15)][wv] = (_Float16)(acc1[r] * SC);
    }
    __syncthreads();

    unsigned short* cp = colp + (size_t)grp * W * H * 4;
#pragma unroll
    for (int k2 = 0; k2 < 2; ++k2) {
        int e = sub + k2 * 256;        // 0..511
        int ilc = e >> 5, ylc = e & 31;
        int ig = i0 + ilc;
        if (ig < W) {
            uint2 v = *(const uint2*)&lx[ilc][ylc][0];
            *(uint2*)&cp[((size_t)ig * H + y0 + ylc) * 4] = v;
        }
    }
}

// ---------------------------------------------------------------------------
// Kernel 4: backprojection, 4 images/block. SINGLE CHANGE vs r14: the lerp
// difference (hi - lo) is hoisted from per-pixel (8192 computations per
// block-angle: 2 v_pk_sub x 4 r-groups per thread) to per-staging-entry
// (768 computations): second LDS array colhd[y] = {col[y+1]-col[y]} pairs.
// Compute loop per r: read base + read diff, pk_fma + pk_add (was: read lo,
// read hi, pk_sub x2, pk_fma, pk_add). Identical fp16 arithmetic -> bit-
// identical output. LDS 25.3 KB (still 4 blocks/CU). Everything else
// (tiling, XCD swizzle, flush cadence, atomics) r14-verbatim.
// ---------------------------------------------------------------------------
__global__ __launch_bounds__(512, 8)
void k_p3(const unsigned short* __restrict__ colp, float* __restrict__ outb) {
    __shared__ __align__(16) H2X2 colh[2][H];    // 12 KB base pairs
    __shared__ __align__(16) H2X2 colhd[2][H];   // 12 KB diff pairs
    __shared__ float2 angs[W / 4];               // 720 B

    const int bid = blockIdx.x;
    const int bz  = bid & 7;             // XCD-local under round-robin dispatch
    const int tle = bid >> 3;            // 0..127: 16 u-tiles x 8 v-tiles
    const int g  = bz >> 2;              // image-group
    const int aq = bz & 3;               // angle quarter
    const int a0 = aq * (W / 4);         // 90 angles per block
    const int u0 = (tle >> 3) * 32;
    const int v0 = (tle & 7) * 64;
    const int tid = threadIdx.x;
    const int lane = tid & 63;
    const int tu = tid >> 6;             // 0..7

    const float vf = (float)(v0 + lane - D / 2);
    float uf[4];
#pragma unroll
    for (int r = 0; r < 4; ++r) uf[r] = (float)(u0 + tu + 8 * r - D / 2);

    const h2 hz = {(__fp16)0.f, (__fp16)0.f};
    float acc[4][4];
    h2 haccA[4], haccB[4];
#pragma unroll
    for (int r = 0; r < 4; ++r) {
#pragma unroll
        for (int nn = 0; nn < 4; ++nn) acc[r][nn] = 0.f;
        haccA[r] = hz;
        haccB[r] = hz;
    }

    const uint2* cp = (const uint2*)colp + (size_t)g * W * H;
    const int y1 = tid;                  // 0..511
    const int y2 = tid + 512;            // 512..767 (tid < 256 only)
    const int y2n = (y2 < H - 1) ? y2 + 1 : y2;   // clamp: entry 767 never read

    if (tid < W / 4) {
        float th = (float)(a0 + tid) * 0.00872664625997164788f;  // pi/360
        float r = SY / 384.0f;
        angs[tid] = make_float2(cosf(th) * r, -sinf(th) * r);
    }
    {
        const int ab = a0 * H;
        uint2 b1 = cp[ab + y1], n1 = cp[ab + y1 + 1];
        colh[0][y1]  = __builtin_bit_cast(H2X2, b1);
        colhd[0][y1] = h2pdiff(n1, b1);
        if (tid < 256) {
            uint2 b2 = cp[ab + y2], n2 = cp[ab + y2n];
            colh[0][y2]  = __builtin_bit_cast(H2X2, b2);
            colhd[0][y2] = h2pdiff(n2, b2);
        }
    }
    __syncthreads();

    for (int j = 0; j < W / 4; ++j) {
        int a = a0 + j;
        int an = (j + 1 < W / 4) ? (a + 1) : a;
        const int ab = an * H;
        uint2 b1 = cp[ab + y1], n1 = cp[ab + y1 + 1];
        uint2 b2 = make_uint2(0u, 0u), n2 = make_uint2(0u, 0u);
        if (tid < 256) { b2 = cp[ab + y2]; n2 = cp[ab + y2n]; }

        const int cb2 = j & 1;
        float2 AB = angs[j];             // LDS broadcast
        float base = fmaf(vf, AB.x, SY);
#pragma unroll
        for (int r = 0; r < 4; ++r) {
            float py = fmaf(uf[r], AB.y, base);
            float wy = __builtin_amdgcn_fractf(py);
            int iy = (int)py;            // trunc == floor (py > 0)
            uint2 bv_raw = *(const uint2*)&colh[cb2][iy];       // ds_read_b64
            uint2 dv_raw = *(const uint2*)&colhd[cb2][iy];      // ds_read_b64
            H2X2 bv = __builtin_bit_cast(H2X2, bv_raw);
            H2X2 dv = __builtin_bit_cast(H2X2, dv_raw);
            h2 wy2 = __builtin_amdgcn_cvt_pkrtz(wy, wy);
            haccA[r] += bv.a + wy2 * dv.a;   // v_pk_fma + v_pk_add
            haccB[r] += bv.b + wy2 * dv.b;
        }

        if ((j & 15) == 15) {
#pragma unroll
            for (int r = 0; r < 4; ++r) {
                acc[r][0] += (float)haccA[r].x;
                acc[r][1] += (float)haccA[r].y;
                acc[r][2] += (float)haccB[r].x;
                acc[r][3] += (float)haccB[r].y;
                haccA[r] = hz;
                haccB[r] = hz;
            }
        }

        colh[cb2 ^ 1][y1]  = __builtin_bit_cast(H2X2, b1);
        colhd[cb2 ^ 1][y1] = h2pdiff(n1, b1);
        if (tid < 256) {
            colh[cb2 ^ 1][y2]  = __builtin_bit_cast(H2X2, b2);
            colhd[cb2 ^ 1][y2] = h2pdiff(n2, b2);
        }
        __syncthreads();
    }

#pragma unroll
    for (int r = 0; r < 4; ++r) {
        acc[r][0] += (float)haccA[r].x;
        acc[r][1] += (float)haccA[r].y;
        acc[r][2] += (float)haccB[r].x;
        acc[r][3] += (float)haccB[r].y;
        int u = u0 + tu + 8 * r;
#pragma unroll
        for (int nn = 0; nn < 4; ++nn) {
            size_t idx = ((size_t)(g * 4 + nn) * D + u) * D + v0 + lane;
            atomicAdd(&outb[idx], acc[r][nn]);
        }
    }
}

// ---------------------------------------------------------------------------
// Workspace layout:
//   [0, 3072)              g (768 floats)
//   [8192, 49152)          Bg (2560 uint4 = 40 KB B-frag table)
//   [65536, 4489216)       colp (2 grp x 360 x 768 x 8B fp16-packed columns)
//   [4489216, 9207808)     rcC (8 x 24 x 384 x 64B bf16 A-frag chunks)
// ---------------------------------------------------------------------------
extern "C" void kernel_launch(void* const* d_in, const int* in_sizes, int n_in,
                              void* d_out, int out_size, void* d_ws, size_t ws_size,
                              hipStream_t stream) {
    const float* radon = (const float*)d_in[0];
    const float* hG    = (const float*)d_in[1];
    float* out = (float*)d_out;

    float* g    = (float*)d_ws;
    uint4* Bg   = (uint4*)((char*)d_ws + 8192);
    unsigned short* colp = (unsigned short*)((char*)d_ws + 65536);
    uint4* rcC  = (uint4*)((char*)d_ws + 4489216);

    k_p0<<<1024, 512, 0, stream>>>(hG, g, (float4*)out);
    k_p1<<<581, 512, 0, stream>>>(radon, g, rcC, Bg);
    k_p2<<<552, 512, 0, stream>>>(rcC, Bg, colp);
    k_p3<<<1024, 512, 0, stream>>>(colp, out);
}